// Round 1
// baseline (360.495 us; speedup 1.0000x reference)
//
#include <hip/hip_runtime.h>
#include <stdint.h>

typedef __attribute__((ext_vector_type(8))) short short8;
typedef __attribute__((ext_vector_type(4))) float f32x4;

#define SCALE_Q 0.17677669529663687f

__device__ __forceinline__ uint16_t f2bf(float f) {
    uint32_t u = __builtin_bit_cast(uint32_t, f);
    u += 0x7FFFu + ((u >> 16) & 1u);
    return (uint16_t)(u >> 16);
}

// ws layout (bytes):
//   0      : wq  bf16 [384][128]  (96 KB)  qkv weights, q-part pre-scaled by SCALE
//   98304  : bq  f32  [384]                qkv bias, q-part pre-scaled
//   99840  : wp  bf16 [128][128]  (32 KB)  proj weights
//   132608 : bT  f32  [4][64][64] (64 KB)  rel-pos bias gathered per head
__global__ void prep_kernel(const float* __restrict__ qkv_w, const float* __restrict__ qkv_b,
                            const float* __restrict__ proj_w, const float* __restrict__ rel_b,
                            uint16_t* __restrict__ wq, float* __restrict__ bq,
                            uint16_t* __restrict__ wp, float* __restrict__ bT) {
    int t = blockIdx.x * 256 + threadIdx.x;
    if (t < 384 * 128) {
        int o = t >> 7;
        float s = (o < 128) ? SCALE_Q : 1.0f;
        wq[t] = f2bf(qkv_w[t] * s);
    }
    if (t < 384) bq[t] = qkv_b[t] * ((t < 128) ? SCALE_Q : 1.0f);
    if (t < 128 * 128) wp[t] = f2bf(proj_w[t]);
    if (t < 4 * 64 * 64) {
        int h = t & 3, nm = t >> 2, n = nm >> 6, m = nm & 63;
        int idx = ((n >> 3) - (m >> 3) + 7) * 15 + ((n & 7) - (m & 7) + 7);
        bT[(h * 64 + n) * 64 + m] = rel_b[idx * 4 + h];
    }
}

// One block per window (batch row). 4 waves = 4 heads.
// LDS region A (40 KB) is phase-aliased: {Q[4][64][40], K[4][64][40]} -> P[4][64][80] -> O[64][136].
__global__ __launch_bounds__(256, 2) void winattn_kernel(
    const float* __restrict__ x, const float* __restrict__ mask,
    const uint16_t* __restrict__ wq, const float* __restrict__ bq,
    const uint16_t* __restrict__ wp, const float* __restrict__ pb,
    const float* __restrict__ bT, float* __restrict__ out)
{
    __shared__ uint16_t regionA[20480]; // 40 KB
    __shared__ uint16_t Vs[4][64][32];  // 16 KB

    uint16_t* Qs = regionA;             // [4][64][40] pad->80B rows (16B-aligned, 2-way max)
    uint16_t* Ks = regionA + 4*64*40;   // [4][64][40]
    uint16_t* Ps = regionA;             // [4][64][80] pad->160B rows
    uint16_t* Os = regionA;             // [64][136]  pad->272B rows

    const int b    = blockIdx.x;
    const int w    = b & 63;            // mask window = b % nW
    const int wid  = threadIdx.x >> 6;
    const int lane = threadIdx.x & 63;
    const int l15  = lane & 15;
    const int lg   = lane >> 4;

    // ---------- Phase 1: QKV = x @ Wqkv^T + bq ----------
    // A-fragments of x loaded straight from global (L1-cached across the 4 waves).
    short8 xa[4][4];
    const float* xb = x + (size_t)b * (64 * 128);
    #pragma unroll
    for (int rt = 0; rt < 4; ++rt) {
      #pragma unroll
      for (int ks = 0; ks < 4; ++ks) {
        const float* p = xb + (rt*16 + l15)*128 + ks*32 + lg*8;
        f32x4 f0 = *(const f32x4*)p;
        f32x4 f1 = *(const f32x4*)(p + 4);
        short8 a;
        a[0]=(short)f2bf(f0[0]); a[1]=(short)f2bf(f0[1]); a[2]=(short)f2bf(f0[2]); a[3]=(short)f2bf(f0[3]);
        a[4]=(short)f2bf(f1[0]); a[5]=(short)f2bf(f1[1]); a[6]=(short)f2bf(f1[2]); a[7]=(short)f2bf(f1[3]);
        xa[rt][ks] = a;
      }
    }
    #pragma unroll
    for (int ct = 0; ct < 6; ++ct) {
        const int obase = wid*96 + ct*16;   // wave-uniform; whole wave hits one (sec, head)
        short8 wb[4];
        #pragma unroll
        for (int ks = 0; ks < 4; ++ks)
            wb[ks] = *(const short8*)(wq + (obase + l15)*128 + ks*32 + lg*8);
        const int o   = obase + l15;
        const int sec = o >> 7;
        const int hh  = (o >> 5) & 3;
        const int d   = o & 31;
        const float bo = bq[o];
        const int stride = (sec == 2) ? 32 : 40;
        uint16_t* dst = (sec == 0) ? (Qs + hh*64*40 + d)
                       : (sec == 1) ? (Ks + hh*64*40 + d)
                       : (&Vs[0][0][0] + hh*64*32 + d);
        #pragma unroll
        for (int rt = 0; rt < 4; ++rt) {
            f32x4 acc = {0.f, 0.f, 0.f, 0.f};
            #pragma unroll
            for (int ks = 0; ks < 4; ++ks)
                acc = __builtin_amdgcn_mfma_f32_16x16x32_bf16(xa[rt][ks], wb[ks], acc, 0, 0, 0);
            #pragma unroll
            for (int r = 0; r < 4; ++r)
                dst[(rt*16 + lg*4 + r) * stride] = f2bf(acc[r] + bo);
        }
    }
    __syncthreads();

    // ---------- Phase 2: S = Q @ K^T + bias + mask; row softmax (in registers) ----------
    const int h = wid;
    short8 qf[4], kf[4];
    #pragma unroll
    for (int rt = 0; rt < 4; ++rt)
        qf[rt] = *(const short8*)(Qs + (h*64 + rt*16 + l15)*40 + lg*8);
    #pragma unroll
    for (int ct = 0; ct < 4; ++ct)
        kf[ct] = *(const short8*)(Ks + (h*64 + ct*16 + l15)*40 + lg*8);
    f32x4 sacc[4][4];
    #pragma unroll
    for (int rt = 0; rt < 4; ++rt) {
      #pragma unroll
      for (int ct = 0; ct < 4; ++ct) {
        f32x4 z = {0.f, 0.f, 0.f, 0.f};
        sacc[rt][ct] = __builtin_amdgcn_mfma_f32_16x16x32_bf16(qf[rt], kf[ct], z, 0, 0, 0);
      }
    }
    const float* bTh = bT + h*64*64;
    const float* mkw = mask + w*64*64;
    float rcp[4][4];
    #pragma unroll
    for (int rt = 0; rt < 4; ++rt) {
      #pragma unroll
      for (int r = 0; r < 4; ++r) {
        const int row = rt*16 + lg*4 + r;
        float v[4];
        #pragma unroll
        for (int ct = 0; ct < 4; ++ct) {
            const int col = ct*16 + l15;
            v[ct] = sacc[rt][ct][r] + bTh[row*64 + col] + mkw[row*64 + col];
        }
        float mx = fmaxf(fmaxf(v[0], v[1]), fmaxf(v[2], v[3]));
        mx = fmaxf(mx, __shfl_xor(mx, 1));
        mx = fmaxf(mx, __shfl_xor(mx, 2));
        mx = fmaxf(mx, __shfl_xor(mx, 4));
        mx = fmaxf(mx, __shfl_xor(mx, 8));
        float s = 0.f;
        #pragma unroll
        for (int ct = 0; ct < 4; ++ct) {
            v[ct] = __expf(v[ct] - mx);
            s += v[ct];
            sacc[rt][ct][r] = v[ct];
        }
        s += __shfl_xor(s, 1);
        s += __shfl_xor(s, 2);
        s += __shfl_xor(s, 4);
        s += __shfl_xor(s, 8);
        rcp[rt][r] = 1.0f / s;   // 1/sum deferred into O epilogue (same lane/reg = same row)
      }
    }
    __syncthreads();   // all waves done reading Q/K before P overwrites the region
    #pragma unroll
    for (int rt = 0; rt < 4; ++rt)
      #pragma unroll
      for (int ct = 0; ct < 4; ++ct)
        #pragma unroll
        for (int r = 0; r < 4; ++r)
            Ps[(h*64 + rt*16 + lg*4 + r)*80 + ct*16 + l15] = f2bf(sacc[rt][ct][r]);
    __syncthreads();

    // ---------- Phase 3: O = P @ V (then * 1/sum) ----------
    short8 pf[4][2];
    #pragma unroll
    for (int rt = 0; rt < 4; ++rt)
      #pragma unroll
      for (int ks = 0; ks < 2; ++ks)
        pf[rt][ks] = *(const short8*)(Ps + (h*64 + rt*16 + l15)*80 + ks*32 + lg*8);
    short8 vf[2][2];
    #pragma unroll
    for (int ks = 0; ks < 2; ++ks) {
      #pragma unroll
      for (int c2 = 0; c2 < 2; ++c2) {
        short8 vv;
        #pragma unroll
        for (int e = 0; e < 8; ++e)
            vv[e] = (short)Vs[h][ks*32 + lg*8 + e][c2*16 + l15];
        vf[ks][c2] = vv;
      }
    }
    f32x4 oacc[4][2];
    #pragma unroll
    for (int rt = 0; rt < 4; ++rt) {
      #pragma unroll
      for (int c2 = 0; c2 < 2; ++c2) {
        f32x4 acc = {0.f, 0.f, 0.f, 0.f};
        #pragma unroll
        for (int ks = 0; ks < 2; ++ks)
            acc = __builtin_amdgcn_mfma_f32_16x16x32_bf16(pf[rt][ks], vf[ks][c2], acc, 0, 0, 0);
        oacc[rt][c2] = acc;
      }
    }
    __syncthreads();   // all waves done reading P before O overwrites the region
    #pragma unroll
    for (int rt = 0; rt < 4; ++rt)
      #pragma unroll
      for (int c2 = 0; c2 < 2; ++c2)
        #pragma unroll
        for (int r = 0; r < 4; ++r)
            Os[(rt*16 + lg*4 + r)*136 + h*32 + c2*16 + l15] = f2bf(oacc[rt][c2][r] * rcp[rt][r]);
    __syncthreads();

    // ---------- Phase 4: out = O @ Wp^T + pb ----------
    short8 of[4][4];
    #pragma unroll
    for (int rt = 0; rt < 4; ++rt)
      #pragma unroll
      for (int ks = 0; ks < 4; ++ks)
        of[rt][ks] = *(const short8*)(Os + (rt*16 + l15)*136 + ks*32 + lg*8);
    float* outb = out + (size_t)b * (64 * 128);
    #pragma unroll
    for (int ct = 0; ct < 2; ++ct) {
        const int c = wid*32 + ct*16 + l15;
        short8 pwf[4];
        #pragma unroll
        for (int ks = 0; ks < 4; ++ks)
            pwf[ks] = *(const short8*)(wp + c*128 + ks*32 + lg*8);
        const float pbias = pb[c];
        #pragma unroll
        for (int rt = 0; rt < 4; ++rt) {
            f32x4 acc = {0.f, 0.f, 0.f, 0.f};
            #pragma unroll
            for (int ks = 0; ks < 4; ++ks)
                acc = __builtin_amdgcn_mfma_f32_16x16x32_bf16(of[rt][ks], pwf[ks], acc, 0, 0, 0);
            #pragma unroll
            for (int r = 0; r < 4; ++r)
                outb[(rt*16 + lg*4 + r)*128 + c] = acc[r] + pbias;
        }
    }
}

extern "C" void kernel_launch(void* const* d_in, const int* in_sizes, int n_in,
                              void* d_out, int out_size, void* d_ws, size_t ws_size,
                              hipStream_t stream) {
    const float* x      = (const float*)d_in[0];
    const float* mask   = (const float*)d_in[1];
    const float* qkv_w  = (const float*)d_in[2];
    const float* qkv_b  = (const float*)d_in[3];
    const float* proj_w = (const float*)d_in[4];
    const float* proj_b = (const float*)d_in[5];
    const float* rel_b  = (const float*)d_in[6];
    float* out = (float*)d_out;

    char* ws = (char*)d_ws;
    uint16_t* wq = (uint16_t*)ws;
    float*    bq = (float*)(ws + 98304);
    uint16_t* wp = (uint16_t*)(ws + 99840);
    float*    bT = (float*)(ws + 132608);

    const int B_ = in_sizes[0] / (64 * 128);   // 8192

    hipLaunchKernelGGL(prep_kernel, dim3(192), dim3(256), 0, stream,
                       qkv_w, qkv_b, proj_w, rel_b, wq, bq, wp, bT);
    hipLaunchKernelGGL(winattn_kernel, dim3(B_), dim3(256), 0, stream,
                       x, mask, wq, bq, wp, proj_b, bT, out);
}